// Round 25
// baseline (1057.203 us; speedup 1.0000x reference)
//
#include <hip/hip_runtime.h>
#include <hip/hip_bf16.h>
#include <math.h>

#define B_ 8
#define L_ 2048
#define DM 256
#define DIP 1064
#define DI 512
#define CD 544
#define DSZ 16
#define NH 8
#define HD 64
#define Q_ 64
#define NC 32
#define ZST 76

typedef __attribute__((ext_vector_type(8))) short bf16x8;
typedef __attribute__((ext_vector_type(4))) float f32x4;

__device__ inline unsigned short f2bf(float f) {
    __hip_bfloat16 h = __float2bfloat16(f);
    return *(unsigned short*)&h;
}
__device__ inline float bf2f(unsigned short u) {
    unsigned int x = ((unsigned int)u) << 16;
    return __uint_as_float(x);
}
__device__ inline float fast_sig(float x) {
    return __builtin_amdgcn_rcpf(1.f + __expf(-x));
}

// ---------------- merged prologue: embed + Wi f2bf + Wo f2bf ----------------
// blocks [0,16384): embed; [16384,17448): Wi; [17448,17960): Wo.
__global__ __launch_bounds__(256) void k_init(const int* __restrict__ x, const float* __restrict__ mask,
                                              const float* __restrict__ emb, const float* __restrict__ pos,
                                              unsigned short* __restrict__ h_bf,
                                              const float* __restrict__ Wi, unsigned short* __restrict__ Wi_bf,
                                              const float* __restrict__ Wo, unsigned short* __restrict__ Wo_bf) {
    int bid = blockIdx.x;
    if (bid < 16384) {
        int i = bid * 256 + threadIdx.x;
        int d = i % DM;
        int bl = i / DM;
        int l = bl % L_;
        int tok = x[bl];
        float v = (emb[tok * DM + d] + pos[l * DM + d]) * mask[bl];
        h_bf[i] = f2bf(v);
    } else if (bid < 16384 + 1064) {
        int i = (bid - 16384) * 256 + threadIdx.x;   // < 272384 = 4*DIP*DM/4
        float4 v = *(const float4*)(Wi + (size_t)i * 4);
        ushort4 o;
        o.x = f2bf(v.x); o.y = f2bf(v.y); o.z = f2bf(v.z); o.w = f2bf(v.w);
        *(ushort4*)(Wi_bf + (size_t)i * 4) = o;
    } else {
        int i = (bid - 16384 - 1064) * 256 + threadIdx.x;   // < 131072 = 4*DM*DI/4
        float4 v = *(const float4*)(Wo + (size_t)i * 4);
        ushort4 o;
        o.x = f2bf(v.x); o.y = f2bf(v.y); o.z = f2bf(v.z); o.w = f2bf(v.w);
        *(ushort4*)(Wo_bf + (size_t)i * 4) = o;
    }
}

// ---------------- bf16 MFMA NT GEMM: in_proj (M=16384, N=1064, K=256) ----------------
__global__ __launch_bounds__(256) void k_gemm_in(const unsigned short* __restrict__ A,
                                                 const unsigned short* __restrict__ Bw,
                                                 unsigned short* __restrict__ Cb, float* __restrict__ dtraw) {
    const int lda = DM, ldb = DM, ldc = DIP, N = DIP, K = DM;
    __shared__ __align__(16) unsigned short Lds[16384];
    unsigned short* Al = Lds;
    unsigned short* Bl = Lds + 8192;
    unsigned short* Clds = Lds;
    int tid = threadIdx.x;
    int l = tid & 63;
    int w = tid >> 6, wr = w >> 1, wc = w & 1;

    int wg = blockIdx.x;
    int xcd = wg & 7;
    int rest = wg >> 3;
    int mgrp = rest / 9;
    int n_tile = rest - mgrp * 9;
    int m_tile = xcd * 16 + mgrp;
    int m0 = m_tile * 128, n0 = n_tile * 128;

    f32x4 zero = {0.f, 0.f, 0.f, 0.f};
    f32x4 acc[4][4];
#pragma unroll
    for (int i = 0; i < 4; i++)
#pragma unroll
        for (int j = 0; j < 4; j++) acc[i][j] = zero;

    int lr = l & 15, kq = l >> 4;
    int aoff = (wr * 64 + lr) * 32 + kq * 8;
    int boff = (wc * 64 + lr) * 32 + kq * 8;

    auto stage = [&](int ks, int buf) {
        int k0 = ks * 32;
#pragma unroll
        for (int q = 0; q < 2; q++) {
            int c = tid + q * 256;
            int row = c >> 2, cc = (c & 3) * 8;
            const unsigned short* ga = A + (size_t)(m0 + row) * lda + k0 + cc;
            __builtin_amdgcn_global_load_lds((const __attribute__((address_space(1))) void*)ga,
                                             (__attribute__((address_space(3))) void*)(&Al[buf * 4096 + c * 8]), 16, 0, 0);
            int rowb = n0 + row;
            if (rowb > N - 1) rowb = N - 1;
            const unsigned short* gb = Bw + (size_t)rowb * ldb + k0 + cc;
            __builtin_amdgcn_global_load_lds((const __attribute__((address_space(1))) void*)gb,
                                             (__attribute__((address_space(3))) void*)(&Bl[buf * 4096 + c * 8]), 16, 0, 0);
        }
    };

    stage(0, 0);
    int ksteps = K / 32;
    for (int s = 0; s < ksteps; s++) {
        int buf = s & 1;
        __syncthreads();
        if (s + 1 < ksteps) stage(s + 1, buf ^ 1);
        bf16x8 a[4], b[4];
#pragma unroll
        for (int i = 0; i < 4; i++) a[i] = *(const bf16x8*)&Al[buf * 4096 + aoff + i * 512];
#pragma unroll
        for (int j = 0; j < 4; j++) b[j] = *(const bf16x8*)&Bl[buf * 4096 + boff + j * 512];
#pragma unroll
        for (int i = 0; i < 4; i++)
#pragma unroll
            for (int j = 0; j < 4; j++)
                acc[i][j] = __builtin_amdgcn_mfma_f32_16x16x32_bf16(a[i], b[j], acc[i][j], 0, 0, 0);
    }

    if (n_tile == 8) {
#pragma unroll
        for (int i = 0; i < 4; i++) {
            int m = m0 + wr * 64 + i * 16 + kq * 4;
#pragma unroll
            for (int j = 0; j < 4; j++) {
                int n = n0 + wc * 64 + j * 16 + lr;
                if (n >= DI + CD && n < N) {
#pragma unroll
                    for (int r = 0; r < 4; r++)
                        dtraw[(size_t)(m + r) * NH + (n - (DI + CD))] = acc[i][j][r];
                }
            }
        }
    }
    __syncthreads();

#pragma unroll
    for (int i = 0; i < 4; i++) {
        int row = wr * 64 + i * 16 + kq * 4;
#pragma unroll
        for (int j = 0; j < 4; j++) {
            int col = wc * 64 + j * 16 + lr;
#pragma unroll
            for (int r = 0; r < 4; r++)
                Clds[(row + r) * 128 + col] = f2bf(acc[i][j][r]);
        }
    }
    __syncthreads();

#pragma unroll
    for (int q = 0; q < 8; q++) {
        int idx = q * 256 + tid;
        int row = idx >> 4, oct = idx & 15;
        int n = n0 + oct * 8;
        if (n < N)
            *(bf16x8*)(Cb + (size_t)(m0 + row) * ldc + n) = *(const bf16x8*)&Clds[row * 128 + oct * 8];
    }
}

// ---------------- fused out-proj GEMM + residual + LayerNorm + mask -> h_bf ----------------
__global__ __launch_bounds__(256) void k_gemm_ln(const unsigned short* __restrict__ A,
                                                 const unsigned short* __restrict__ Bw,
                                                 unsigned short* __restrict__ hbf,
                                                 const float* __restrict__ lnw, const float* __restrict__ lnb,
                                                 const float* __restrict__ mask) {
    __shared__ unsigned short Al[2][32 * 32];
    __shared__ unsigned short Bl[2][256 * 32];
    __shared__ float part_s[32][4], part_q[32][4];
    int tid = threadIdx.x;
    int l = tid & 63;
    int w = tid >> 6;
    int m0 = blockIdx.x * 32;
    int lr = l & 15, kq = l >> 4;

    f32x4 zero = {0.f, 0.f, 0.f, 0.f};
    f32x4 acc[2][4];
#pragma unroll
    for (int i = 0; i < 2; i++)
#pragma unroll
        for (int j = 0; j < 4; j++) acc[i][j] = zero;

    auto stage = [&](int ks, int buf) {
        int k0 = ks * 32;
        if (tid < 128) {
            int row = tid >> 2, cc = (tid & 3) * 8;
            const unsigned short* ga = A + (size_t)(m0 + row) * DI + k0 + cc;
            __builtin_amdgcn_global_load_lds((const __attribute__((address_space(1))) void*)ga,
                                             (__attribute__((address_space(3))) void*)(&Al[buf][tid * 8]), 16, 0, 0);
        }
#pragma unroll
        for (int q = 0; q < 4; q++) {
            int c = tid + q * 256;
            int row = c >> 2, cc = (c & 3) * 8;
            const unsigned short* gb = Bw + (size_t)row * DI + k0 + cc;
            __builtin_amdgcn_global_load_lds((const __attribute__((address_space(1))) void*)gb,
                                             (__attribute__((address_space(3))) void*)(&Bl[buf][c * 8]), 16, 0, 0);
        }
    };

    stage(0, 0);
    const int ksteps = DI / 32;
    for (int s = 0; s < ksteps; s++) {
        int buf = s & 1;
        __syncthreads();
        if (s + 1 < ksteps) stage(s + 1, buf ^ 1);
        bf16x8 a[2], b[4];
#pragma unroll
        for (int i = 0; i < 2; i++) a[i] = *(const bf16x8*)&Al[buf][(i * 16 + lr) * 32 + kq * 8];
#pragma unroll
        for (int j = 0; j < 4; j++) b[j] = *(const bf16x8*)&Bl[buf][(w * 64 + j * 16 + lr) * 32 + kq * 8];
#pragma unroll
        for (int i = 0; i < 2; i++)
#pragma unroll
            for (int j = 0; j < 4; j++)
                acc[i][j] = __builtin_amdgcn_mfma_f32_16x16x32_bf16(a[i], b[j], acc[i][j], 0, 0, 0);
    }

#pragma unroll
    for (int i = 0; i < 2; i++) {
#pragma unroll
        for (int r = 0; r < 4; r++) {
            int row = i * 16 + kq * 4 + r;
            const unsigned short* hrow = hbf + (size_t)(m0 + row) * DM + w * 64 + lr;
#pragma unroll
            for (int j = 0; j < 4; j++)
                acc[i][j][r] += bf2f(hrow[j * 16]);
        }
    }
#pragma unroll
    for (int i = 0; i < 2; i++) {
#pragma unroll
        for (int r = 0; r < 4; r++) {
            float sv = acc[i][0][r] + acc[i][1][r] + acc[i][2][r] + acc[i][3][r];
            float qv = acc[i][0][r] * acc[i][0][r] + acc[i][1][r] * acc[i][1][r] +
                       acc[i][2][r] * acc[i][2][r] + acc[i][3][r] * acc[i][3][r];
#pragma unroll
            for (int off = 1; off < 16; off <<= 1) {
                sv += __shfl_xor(sv, off);
                qv += __shfl_xor(qv, off);
            }
            if (lr == 0) {
                int row = i * 16 + kq * 4 + r;
                part_s[row][w] = sv;
                part_q[row][w] = qv;
            }
        }
    }
    __syncthreads();
    float4 wv4 = make_float4(lnw[w * 64 + 0 * 16 + lr], lnw[w * 64 + 1 * 16 + lr],
                             lnw[w * 64 + 2 * 16 + lr], lnw[w * 64 + 3 * 16 + lr]);
    float4 bv4 = make_float4(lnb[w * 64 + 0 * 16 + lr], lnb[w * 64 + 1 * 16 + lr],
                             lnb[w * 64 + 2 * 16 + lr], lnb[w * 64 + 3 * 16 + lr]);
#pragma unroll
    for (int i = 0; i < 2; i++) {
#pragma unroll
        for (int r = 0; r < 4; r++) {
            int row = i * 16 + kq * 4 + r;
            float sum = part_s[row][0] + part_s[row][1] + part_s[row][2] + part_s[row][3];
            float sq  = part_q[row][0] + part_q[row][1] + part_q[row][2] + part_q[row][3];
            float mu = sum * (1.f / DM);
            float var = sq * (1.f / DM) - mu * mu;
            float rs = rsqrtf(var + 1e-5f);
            float mk = mask[m0 + row];
            unsigned short* drow = hbf + (size_t)(m0 + row) * DM + w * 64 + lr;
            float wr_[4] = {wv4.x, wv4.y, wv4.z, wv4.w};
            float br_[4] = {bv4.x, bv4.y, bv4.z, bv4.w};
#pragma unroll
            for (int j = 0; j < 4; j++) {
                float o = ((acc[i][j][r] - mu) * rs * wr_[j] + br_[j]) * mk;
                drow[j * 16] = f2bf(o);
            }
        }
    }
}

// ---------------- B/C conv+silu + per-head dt/cumsum precompute ----------------
__global__ __launch_bounds__(256) void k_bcdt(const unsigned short* __restrict__ zxb,
                                              const float* __restrict__ cw, const float* __restrict__ cb,
                                              const float* __restrict__ dtraw, const float* __restrict__ dtb,
                                              const float* __restrict__ Alog,
                                              unsigned short* __restrict__ BCc,
                                              float* __restrict__ dts_g, float* __restrict__ coefS_g,
                                              float* __restrict__ cumL, float* __restrict__ Pg) {
    int pair = blockIdx.x;
    int b = pair >> 5, c = pair & 31;
    int t0 = c * Q_;
    int tid = threadIdx.x;
    int t = tid & 63, oct = tid >> 6;
    {
        int lg0 = t0 + t - 3;
        const unsigned short* base = zxb + ((size_t)b * L_ + lg0) * DIP + 1024 + oct * 8;
        bf16x8 rows[4];
#pragma unroll
        for (int k = 0; k < 4; k++) {
            if (lg0 + k >= 0) rows[k] = *(const bf16x8*)(base + (size_t)k * DIP);
            else {
#pragma unroll
                for (int j = 0; j < 8; j++) rows[k][j] = 0;
            }
        }
        bf16x8 o;
#pragma unroll
        for (int j = 0; j < 8; j++) {
            int cc = DI + oct * 8 + j;
            float acc = cb[cc];
            acc = fmaf(bf2f((unsigned short)rows[0][j]), cw[cc * 4 + 0], acc);
            acc = fmaf(bf2f((unsigned short)rows[1][j]), cw[cc * 4 + 1], acc);
            acc = fmaf(bf2f((unsigned short)rows[2][j]), cw[cc * 4 + 2], acc);
            acc = fmaf(bf2f((unsigned short)rows[3][j]), cw[cc * 4 + 3], acc);
            float s = acc * fast_sig(acc);
            o[j] = (short)f2bf(s);
        }
        *(bf16x8*)(BCc + ((size_t)(b * L_ + t0 + t)) * 32 + oct * 8) = o;
    }
#pragma unroll
    for (int ho = 0; ho < 2; ho++) {
        int h = oct * 2 + ho;
        int bh = b * 8 + h;
        float raw = dtraw[(size_t)(b * L_ + t0 + t) * NH + h] + dtb[h];
        float dtv = (raw > 20.f) ? raw : log1pf(__expf(raw));
        float v = -__expf(Alog[h]) * dtv;
#pragma unroll
        for (int off = 1; off < 64; off <<= 1) {
            float u = __shfl_up(v, off);
            if (t >= off) v += u;
        }
        float lend = __shfl(v, 63);
        size_t base = (size_t)(bh * NC + c) * Q_ + t;
        dts_g[base] = dtv;
        cumL[base] = v;
        coefS_g[base] = __expf(lend - v) * dtv;
        if (t == 63) Pg[bh * NC + c] = __expf(v);
    }
}

// ---------------- fused conv+silu + chunked scan stage 1 (MFMA); vector Y store ----------------
__global__ __launch_bounds__(256) void k_scan1c(const unsigned short* __restrict__ zxb,
                                                const unsigned short* __restrict__ BCc,
                                                const float* __restrict__ dts_g, const float* __restrict__ coefS_g,
                                                const float* __restrict__ cumL,
                                                const float* __restrict__ cw, const float* __restrict__ cb,
                                                const float* __restrict__ Dp,
                                                unsigned short* __restrict__ ybuf, unsigned short* __restrict__ Sg) {
    int wg = blockIdx.x;
    int xcd = wg & 7;
    int rest = wg >> 3;
    int slot = rest >> 3;
    int h = rest & 7;
    int pair = slot * 8 + xcd;
    int b = pair >> 5, c = pair & 31;
    int bh = b * 8 + h;
    int tid = threadIdx.x;
    int t0 = c * Q_;
    int w = tid >> 6, l = tid & 63;
    int lr = l & 15, kq = l >> 4;

    __shared__ __align__(16) unsigned short Zl[67 * ZST];
    __shared__ __align__(16) unsigned short Xt[Q_ * 72];
    __shared__ __align__(16) unsigned short Pool[4096];
    __shared__ __align__(16) unsigned short Btw[DSZ * 72];
    __shared__ float Lc[Q_], dts[Q_], coefS[Q_];
    unsigned short* Mbf = Zl;
    unsigned short* Cbf = Pool;
    unsigned short* Bbf = Pool + 2048;
    unsigned short* Ylds = Pool;

    float Dval = Dp[h];

    for (int idx = tid; idx < 67 * 8; idx += 256) {
        int rr = idx >> 3, seg = idx & 7;
        int lg = t0 - 3 + rr;
        bf16x8 v;
        if (lg >= 0) {
            v = *(const bf16x8*)(zxb + (size_t)(b * L_ + lg) * DIP + DI + h * HD + seg * 8);
        } else {
#pragma unroll
            for (int j = 0; j < 8; j++) v[j] = 0;
        }
        *(ushort4*)&Zl[rr * ZST + seg * 8]     = *(ushort4*)&v;
        *(ushort4*)&Zl[rr * ZST + seg * 8 + 4] = *((ushort4*)&v + 1);
    }
    {
        bf16x8 z8;
#pragma unroll
        for (int j = 0; j < 8; j++) z8[j] = 0;
        *(bf16x8*)&Cbf[tid * 8] = z8;
        *(bf16x8*)&Bbf[tid * 8] = z8;
    }
    if (tid < 64) {
        size_t base = (size_t)(bh * NC + c) * Q_ + tid;
        dts[tid] = dts_g[base];
        Lc[tid] = cumL[base];
        coefS[tid] = coefS_g[base];
    }
    __syncthreads();

    float xreg[4][4];
#pragma unroll
    for (int pt = 0; pt < 4; pt++) {
#pragma unroll
        for (int r = 0; r < 4; r++) {
            int t = w * 16 + kq * 4 + r;
            int p = pt * 16 + lr;
            int cc = h * HD + p;
            float acc = cb[cc];
#pragma unroll
            for (int k = 0; k < 4; k++)
                acc = fmaf(bf2f(Zl[(t + k) * ZST + p]), cw[cc * 4 + k], acc);
            float s = acc * fast_sig(acc);
            xreg[pt][r] = s;
            Xt[p * 72 + t] = f2bf(s);
        }
    }
    {
        int t = tid & 63, oct = tid >> 6;
        bf16x8 v = *(const bf16x8*)(BCc + ((size_t)(b * L_ + t0 + t)) * 32 + oct * 8);
        float dtv = dts[t], cfv = coefS[t];
#pragma unroll
        for (int j = 0; j < 8; j++) {
            int n32 = oct * 8 + j;
            float s = bf2f((unsigned short)v[j]);
            if (n32 < 16) {
                int n = n32;
                Bbf[t * 32 + (((n >> 3) ^ (t & 3)) * 8) + (n & 7)] = f2bf(dtv * s);
                Btw[n * 72 + t] = f2bf(cfv * s);
            } else {
                int n = n32 - 16;
                Cbf[t * 32 + (((n >> 3) ^ (t & 3)) * 8) + (n & 7)] = (unsigned short)v[j];
            }
        }
    }
    __syncthreads();

    f32x4 zero = {0.f, 0.f, 0.f, 0.f};

    f32x4 cbt[4];
    {
        bf16x8 af = *(const bf16x8*)&Cbf[(w * 16 + lr) * 32 + ((kq ^ (lr & 3)) * 8)];
#pragma unroll
        for (int st = 0; st < 4; st++) {
            bf16x8 bf = *(const bf16x8*)&Bbf[(st * 16 + lr) * 32 + ((kq ^ (lr & 3)) * 8)];
            cbt[st] = __builtin_amdgcn_mfma_f32_16x16x32_bf16(af, bf, zero, 0, 0, 0);
        }
    }
#pragma unroll
    for (int st = 0; st < 4; st++) {
#pragma unroll
        for (int r = 0; r < 4; r++) {
            int t = w * 16 + kq * 4 + r;
            int s = st * 16 + lr;
            float m = (s <= t) ? __expf(Lc[t] - Lc[s]) * cbt[st][r] : 0.f;
            Mbf[t * 64 + (((s >> 3) ^ (t & 7)) * 8) + (s & 7)] = f2bf(m);
        }
    }
    __syncthreads();

    {
        f32x4 acc[4];
#pragma unroll
        for (int pt = 0; pt < 4; pt++) acc[pt] = zero;
#pragma unroll
        for (int ks = 0; ks < 2; ks++) {
            bf16x8 af = *(const bf16x8*)&Mbf[(w * 16 + lr) * 64 + (((ks * 4 + kq) ^ (lr & 7)) * 8)];
#pragma unroll
            for (int pt = 0; pt < 4; pt++) {
                bf16x8 bf = *(const bf16x8*)&Xt[(pt * 16 + lr) * 72 + ks * 32 + kq * 8];
                acc[pt] = __builtin_amdgcn_mfma_f32_16x16x32_bf16(af, bf, acc[pt], 0, 0, 0);
            }
        }
#pragma unroll
        for (int pt = 0; pt < 4; pt++) {
#pragma unroll
            for (int r = 0; r < 4; r++) {
                int t = w * 16 + kq * 4 + r;
                int p = pt * 16 + lr;
                Ylds[t * 64 + p] = f2bf(acc[pt][r] + Dval * xreg[pt][r]);
            }
        }
    }

    {
        f32x4 sacc = zero;
#pragma unroll
        for (int ks = 0; ks < 2; ks++) {
            bf16x8 af = *(const bf16x8*)&Xt[(w * 16 + lr) * 72 + ks * 32 + kq * 8];
            bf16x8 bf = *(const bf16x8*)&Btw[lr * 72 + ks * 32 + kq * 8];
            sacc = __builtin_amdgcn_mfma_f32_16x16x32_bf16(af, bf, sacc, 0, 0, 0);
        }
#pragma unroll
        for (int r = 0; r < 4; r++) {
            int p = w * 16 + kq * 4 + r;
            Sg[((size_t)(bh * NC + c) * HD + p) * DSZ + lr] = f2bf(sacc[r]);
        }
    }
    __syncthreads();

    {
        unsigned short* base_y = ybuf + ((size_t)b * L_ + t0) * DI + h * HD;
#pragma unroll
        for (int q = 0; q < 2; q++) {
            int idx = q * 256 + tid;
            int t = idx >> 3, oct = idx & 7;
            *(bf16x8*)(base_y + (size_t)t * DI + oct * 8) = *(const bf16x8*)&Ylds[t * 64 + oct * 8];
        }
    }
}

// ---------------- chunked scan stage 2: bf16 S/H, fp32 prefix in registers ----------------
__global__ __launch_bounds__(256) void k_scan2(const unsigned short* __restrict__ Sg, const float* __restrict__ Pg,
                                               unsigned short* __restrict__ Hg) {
    int bh = blockIdx.x;
    int tid = threadIdx.x;
    int p = tid >> 2, n0 = (tid & 3) * 4;
    float4 H = make_float4(0.f, 0.f, 0.f, 0.f);
    for (int g = 0; g < NC / 8; g++) {
        ushort4 S[8];
#pragma unroll
        for (int j = 0; j < 8; j++)
            S[j] = *(const ushort4*)(Sg + (((size_t)bh * NC + g * 8 + j) * HD + p) * DSZ + n0);
#pragma unroll
        for (int j = 0; j < 8; j++) {
            int cc = g * 8 + j;
            ushort4 ho;
            ho.x = f2bf(H.x); ho.y = f2bf(H.y); ho.z = f2bf(H.z); ho.w = f2bf(H.w);
            *(ushort4*)(Hg + (((size_t)bh * NC + cc) * HD + p) * DSZ + n0) = ho;
            float P = Pg[bh * NC + cc];
            H.x = fmaf(P, H.x, bf2f(S[j].x));
            H.y = fmaf(P, H.y, bf2f(S[j].y));
            H.z = fmaf(P, H.z, bf2f(S[j].z));
            H.w = fmaf(P, H.w, bf2f(S[j].w));
        }
    }
}

// ---------------- fused scan stage 3 + gated RMSNorm -> bf16 yn ----------------
// grid 512 (XCD-swizzled): block = (b, chunk, half) = 32 rows; 2 row-groups/thread.
__global__ __launch_bounds__(256) void k_scan3g(const unsigned short* __restrict__ ybuf,
                                                const unsigned short* __restrict__ zxb,
                                                const unsigned short* __restrict__ Hg, const float* __restrict__ cumLg,
                                                const unsigned short* __restrict__ BCc, const float* __restrict__ nw,
                                                unsigned short* __restrict__ yn_bf) {
    int wg = blockIdx.x;
    int xcd = wg & 7;
    int rest = wg >> 3;                 // 0..63
    int chunk_local = rest >> 1;        // 0..31
    int sub = rest & 1;
    int chunk_global = xcd * 32 + chunk_local;   // 0..255
    int b = chunk_global >> 5, c64 = chunk_global & 31;
    int t0 = c64 * 64 + sub * 32;
    int tid = threadIdx.x;
    __shared__ float Hsn[DSZ * 576];
    __shared__ float Lq[NH][32];

    {
        int p = tid & 63, hp = tid >> 6;
#pragma unroll
        for (int ho = 0; ho < 2; ho++) {
            int hh = hp * 2 + ho;
            const unsigned short* src = Hg + (((size_t)(b * NH + hh) * NC + c64) * HD + p) * DSZ;
            float* dst = &Hsn[p * 9 + hh];
            bf16x8 lo = *(const bf16x8*)(src);
            bf16x8 hi = *(const bf16x8*)(src + 8);
#pragma unroll
            for (int nq = 0; nq < 8; nq++) {
                dst[nq * 576] = bf2f((unsigned short)lo[nq]);
                dst[(nq + 8) * 576] = bf2f((unsigned short)hi[nq]);
            }
        }
    }
    {
        int hh = tid >> 5, t = tid & 31;
        Lq[hh][t] = cumLg[((size_t)(b * NH + hh) * NC + c64) * Q_ + sub * 32 + t];
    }
    __syncthreads();

    int trow = tid >> 4, q16 = tid & 15;
    int hh = q16 >> 1, p0 = (q16 & 1) * 32;

#pragma unroll
    for (int rg = 0; rg < 2; rg++) {
        int tl = rg * 16 + trow;            // 0..31
        size_t bl = (size_t)b * L_ + t0 + tl;
        float ef = __expf(Lq[hh][tl]);

        float Cr[16];
        {
            const unsigned short* crow = BCc + bl * 32 + 16;
            bf16x8 lo = *(const bf16x8*)(crow);
            bf16x8 hi = *(const bf16x8*)(crow + 8);
#pragma unroll
            for (int k = 0; k < 8; k++) {
                Cr[k] = ef * bf2f((unsigned short)lo[k]);
                Cr[k + 8] = ef * bf2f((unsigned short)hi[k]);
            }
        }

        const unsigned short* yrow = ybuf + bl * DI + hh * HD + p0;
        const unsigned short* zrow = zxb + bl * DIP + hh * HD + p0;
        unsigned short yv[32], zv[32];
#pragma unroll
        for (int k = 0; k < 4; k++) *(bf16x8*)&yv[k * 8] = *(const bf16x8*)(yrow + k * 8);
#pragma unroll
        for (int k = 0; k < 4; k++) *(bf16x8*)&zv[k * 8] = *(const bf16x8*)(zrow + k * 8);

        float yg[32];
        float ss = 0.f;
#pragma unroll
        for (int j = 0; j < 32; j++) {
            const float* hp_ = &Hsn[(p0 + j) * 9 + hh];
            float d = 0.f;
#pragma unroll
            for (int n = 0; n < DSZ; n++) d = fmaf(Cr[n], hp_[n * 576], d);
            float y = bf2f(yv[j]) + d;
            float z = bf2f(zv[j]);
            yg[j] = y * z * fast_sig(z);
            ss = fmaf(yg[j], yg[j], ss);
        }
        ss += __shfl_xor(ss, 1);
        ss += __shfl_xor(ss, 2);
        ss += __shfl_xor(ss, 4);
        ss += __shfl_xor(ss, 8);
        float r = rsqrtf(ss * (1.f / DI) + 1e-5f);

        const float* nwp = nw + hh * HD + p0;
        unsigned short* dst = yn_bf + bl * DI + hh * HD + p0;
#pragma unroll
        for (int k = 0; k < 4; k++) {
            bf16x8 o;
#pragma unroll
            for (int j = 0; j < 8; j++) o[j] = (short)f2bf(yg[k * 8 + j] * r * nwp[k * 8 + j]);
            *(bf16x8*)(dst + k * 8) = o;
        }
    }
}

// ---------------- 2-stage mean-pool + classifier (bf16 input) ----------------
__global__ __launch_bounds__(256) void k_pool1(const unsigned short* __restrict__ h, float* __restrict__ part) {
    int b = blockIdx.x, g = blockIdx.y, d = threadIdx.x;
    const unsigned short* hb = h + ((size_t)b * L_ + g * 128) * DM + d;
    float s = 0.f;
    for (int l = 0; l < 128; l++) s += bf2f(hb[(size_t)l * DM]);
    part[((size_t)b * 16 + g) * DM + d] = s;
}

__global__ __launch_bounds__(256) void k_pool2(const float* __restrict__ part, const float* __restrict__ cw,
                                               const float* __restrict__ cb, float* __restrict__ out) {
    int b = blockIdx.x, tid = threadIdx.x;
    float s = 0.f;
#pragma unroll
    for (int g = 0; g < 16; g++) s += part[((size_t)b * 16 + g) * DM + tid];
    s *= (1.0f / L_);
    float p0 = s * cw[tid];
    float p1 = s * cw[DM + tid];
#pragma unroll
    for (int m = 1; m < 64; m <<= 1) {
        p0 += __shfl_xor(p0, m);
        p1 += __shfl_xor(p1, m);
    }
    __shared__ float r0[4], r1[4];
    if ((tid & 63) == 0) { r0[tid >> 6] = p0; r1[tid >> 6] = p1; }
    __syncthreads();
    if (tid == 0) {
        out[b * 2 + 0] = r0[0] + r0[1] + r0[2] + r0[3] + cb[0];
        out[b * 2 + 1] = r1[0] + r1[1] + r1[2] + r1[3] + cb[1];
    }
}

extern "C" void kernel_launch(void* const* d_in, const int* in_sizes, int n_in,
                              void* d_out, int out_size, void* d_ws, size_t ws_size,
                              hipStream_t stream) {
    const int*   x    = (const int*)d_in[0];
    const float* mask = (const float*)d_in[1];
    const float* emb  = (const float*)d_in[2];
    const float* pos  = (const float*)d_in[3];
    const float* Wi   = (const float*)d_in[4];
    const float* cw   = (const float*)d_in[5];
    const float* cb   = (const float*)d_in[6];
    const float* dtb  = (const float*)d_in[7];
    const float* Alog = (const float*)d_in[8];
    const float* Dp   = (const float*)d_in[9];
    const float* nw   = (const float*)d_in[10];
    const float* Wo   = (const float*)d_in[11];
    const float* lnw  = (const float*)d_in[12];
    const float* lnb  = (const float*)d_in[13];
    const float* clsw = (const float*)d_in[14];
    const float* clsb = (const float*)d_in[15];
    float* out = (float*)d_out;

    float* ws     = (float*)d_ws;
    float* dtraw  = ws;
    float* Pg     = dtraw + (size_t)B_ * L_ * NH;
    float* cumL   = Pg + (size_t)64 * NC;
    float* dts_g  = cumL + (size_t)64 * NC * Q_;
    float* coefSg = dts_g + (size_t)64 * NC * Q_;
    float* pool   = coefSg + (size_t)64 * NC * Q_;
    unsigned short* Sg    = (unsigned short*)(pool + (size_t)B_ * 16 * DM);
    unsigned short* Hg    = Sg + (size_t)64 * NC * HD * DSZ;
    unsigned short* BCc   = Hg + (size_t)64 * NC * HD * DSZ;
    unsigned short* zxb   = BCc + (size_t)B_ * L_ * 32;
    unsigned short* ybuf  = zxb + (size_t)B_ * L_ * DIP;
    unsigned short* h_bf  = ybuf + (size_t)B_ * L_ * DI;
    unsigned short* yn_bf = h_bf + (size_t)B_ * L_ * DM;
    unsigned short* Wi_bf = yn_bf + (size_t)B_ * L_ * DI;
    unsigned short* Wo_bf = Wi_bf + (size_t)4 * DIP * DM;

    // merged prologue: embed + weight conversions
    k_init<<<16384 + 1064 + 512, 256, 0, stream>>>(x, mask, emb, pos, h_bf, Wi, Wi_bf, Wo, Wo_bf);

    for (int i = 0; i < 4; i++) {
        k_gemm_in<<<128 * 9, 256, 0, stream>>>(
            h_bf, Wi_bf + (size_t)i * DIP * DM, zxb, dtraw);
        k_bcdt<<<B_ * NC, 256, 0, stream>>>(
            zxb, cw + (size_t)i * CD * 4, cb + i * CD, dtraw, dtb + i * NH, Alog + i * NH,
            BCc, dts_g, coefSg, cumL, Pg);
        k_scan1c<<<2048, 256, 0, stream>>>(
            zxb, BCc, dts_g, coefSg, cumL, cw + (size_t)i * CD * 4, cb + i * CD,
            Dp + i * NH, ybuf, Sg);
        k_scan2<<<64, 256, 0, stream>>>(Sg, Pg, Hg);
        k_scan3g<<<512, 256, 0, stream>>>(ybuf, zxb, Hg, cumL, BCc, nw + (size_t)i * DI, yn_bf);
        k_gemm_ln<<<B_ * L_ / 32, 256, 0, stream>>>(
            yn_bf, Wo_bf + (size_t)i * DM * DI, h_bf, lnw, lnb, mask);
    }

    k_pool1<<<dim3(B_, 16), 256, 0, stream>>>(h_bf, pool);
    k_pool2<<<B_, 256, 0, stream>>>(pool, clsw, clsb, out);
}

// Round 26
// 343.917 us; speedup vs baseline: 3.0740x; 3.0740x over previous
//
#include <hip/hip_runtime.h>
#include <hip/hip_bf16.h>
#include <math.h>

#define B_ 8
#define L_ 2048
#define DM 256
#define DIP 1064
#define DI 512
#define CD 544
#define DSZ 16
#define NH 8
#define HD 64
#define Q_ 64
#define NC 32
#define ZST 76

typedef __attribute__((ext_vector_type(8))) short bf16x8;
typedef __attribute__((ext_vector_type(4))) float f32x4;

__device__ inline unsigned short f2bf(float f) {
    __hip_bfloat16 h = __float2bfloat16(f);
    return *(unsigned short*)&h;
}
__device__ inline float bf2f(unsigned short u) {
    unsigned int x = ((unsigned int)u) << 16;
    return __uint_as_float(x);
}
__device__ inline float fast_sig(float x) {
    return __builtin_amdgcn_rcpf(1.f + __expf(-x));
}

// ---------------- merged prologue: embed + Wi f2bf + Wo f2bf ----------------
__global__ __launch_bounds__(256) void k_init(const int* __restrict__ x, const float* __restrict__ mask,
                                              const float* __restrict__ emb, const float* __restrict__ pos,
                                              unsigned short* __restrict__ h_bf,
                                              const float* __restrict__ Wi, unsigned short* __restrict__ Wi_bf,
                                              const float* __restrict__ Wo, unsigned short* __restrict__ Wo_bf) {
    int bid = blockIdx.x;
    if (bid < 16384) {
        int i = bid * 256 + threadIdx.x;
        int d = i % DM;
        int bl = i / DM;
        int l = bl % L_;
        int tok = x[bl];
        float v = (emb[tok * DM + d] + pos[l * DM + d]) * mask[bl];
        h_bf[i] = f2bf(v);
    } else if (bid < 16384 + 1064) {
        int i = (bid - 16384) * 256 + threadIdx.x;
        float4 v = *(const float4*)(Wi + (size_t)i * 4);
        ushort4 o;
        o.x = f2bf(v.x); o.y = f2bf(v.y); o.z = f2bf(v.z); o.w = f2bf(v.w);
        *(ushort4*)(Wi_bf + (size_t)i * 4) = o;
    } else {
        int i = (bid - 16384 - 1064) * 256 + threadIdx.x;
        float4 v = *(const float4*)(Wo + (size_t)i * 4);
        ushort4 o;
        o.x = f2bf(v.x); o.y = f2bf(v.y); o.z = f2bf(v.z); o.w = f2bf(v.w);
        *(ushort4*)(Wo_bf + (size_t)i * 4) = o;
    }
}

// ---------------- bf16 MFMA NT GEMM: in_proj (M=16384, N=1064, K=256) ----------------
__global__ __launch_bounds__(256) void k_gemm_in(const unsigned short* __restrict__ A,
                                                 const unsigned short* __restrict__ Bw,
                                                 unsigned short* __restrict__ Cb, float* __restrict__ dtraw) {
    const int lda = DM, ldb = DM, ldc = DIP, N = DIP, K = DM;
    __shared__ __align__(16) unsigned short Lds[16384];
    unsigned short* Al = Lds;
    unsigned short* Bl = Lds + 8192;
    unsigned short* Clds = Lds;
    int tid = threadIdx.x;
    int l = tid & 63;
    int w = tid >> 6, wr = w >> 1, wc = w & 1;

    int wg = blockIdx.x;
    int xcd = wg & 7;
    int rest = wg >> 3;
    int mgrp = rest / 9;
    int n_tile = rest - mgrp * 9;
    int m_tile = xcd * 16 + mgrp;
    int m0 = m_tile * 128, n0 = n_tile * 128;

    f32x4 zero = {0.f, 0.f, 0.f, 0.f};
    f32x4 acc[4][4];
#pragma unroll
    for (int i = 0; i < 4; i++)
#pragma unroll
        for (int j = 0; j < 4; j++) acc[i][j] = zero;

    int lr = l & 15, kq = l >> 4;
    int aoff = (wr * 64 + lr) * 32 + kq * 8;
    int boff = (wc * 64 + lr) * 32 + kq * 8;

    auto stage = [&](int ks, int buf) {
        int k0 = ks * 32;
#pragma unroll
        for (int q = 0; q < 2; q++) {
            int c = tid + q * 256;
            int row = c >> 2, cc = (c & 3) * 8;
            const unsigned short* ga = A + (size_t)(m0 + row) * lda + k0 + cc;
            __builtin_amdgcn_global_load_lds((const __attribute__((address_space(1))) void*)ga,
                                             (__attribute__((address_space(3))) void*)(&Al[buf * 4096 + c * 8]), 16, 0, 0);
            int rowb = n0 + row;
            if (rowb > N - 1) rowb = N - 1;
            const unsigned short* gb = Bw + (size_t)rowb * ldb + k0 + cc;
            __builtin_amdgcn_global_load_lds((const __attribute__((address_space(1))) void*)gb,
                                             (__attribute__((address_space(3))) void*)(&Bl[buf * 4096 + c * 8]), 16, 0, 0);
        }
    };

    stage(0, 0);
    int ksteps = K / 32;
    for (int s = 0; s < ksteps; s++) {
        int buf = s & 1;
        __syncthreads();
        if (s + 1 < ksteps) stage(s + 1, buf ^ 1);
        bf16x8 a[4], b[4];
#pragma unroll
        for (int i = 0; i < 4; i++) a[i] = *(const bf16x8*)&Al[buf * 4096 + aoff + i * 512];
#pragma unroll
        for (int j = 0; j < 4; j++) b[j] = *(const bf16x8*)&Bl[buf * 4096 + boff + j * 512];
#pragma unroll
        for (int i = 0; i < 4; i++)
#pragma unroll
            for (int j = 0; j < 4; j++)
                acc[i][j] = __builtin_amdgcn_mfma_f32_16x16x32_bf16(a[i], b[j], acc[i][j], 0, 0, 0);
    }

    if (n_tile == 8) {
#pragma unroll
        for (int i = 0; i < 4; i++) {
            int m = m0 + wr * 64 + i * 16 + kq * 4;
#pragma unroll
            for (int j = 0; j < 4; j++) {
                int n = n0 + wc * 64 + j * 16 + lr;
                if (n >= DI + CD && n < N) {
#pragma unroll
                    for (int r = 0; r < 4; r++)
                        dtraw[(size_t)(m + r) * NH + (n - (DI + CD))] = acc[i][j][r];
                }
            }
        }
    }
    __syncthreads();

#pragma unroll
    for (int i = 0; i < 4; i++) {
        int row = wr * 64 + i * 16 + kq * 4;
#pragma unroll
        for (int j = 0; j < 4; j++) {
            int col = wc * 64 + j * 16 + lr;
#pragma unroll
            for (int r = 0; r < 4; r++)
                Clds[(row + r) * 128 + col] = f2bf(acc[i][j][r]);
        }
    }
    __syncthreads();

#pragma unroll
    for (int q = 0; q < 8; q++) {
        int idx = q * 256 + tid;
        int row = idx >> 4, oct = idx & 15;
        int n = n0 + oct * 8;
        if (n < N)
            *(bf16x8*)(Cb + (size_t)(m0 + row) * ldc + n) = *(const bf16x8*)&Clds[row * 128 + oct * 8];
    }
}

// ---------------- fused out-proj GEMM + residual + LayerNorm + mask -> h_bf ----------------
__global__ __launch_bounds__(256) void k_gemm_ln(const unsigned short* __restrict__ A,
                                                 const unsigned short* __restrict__ Bw,
                                                 unsigned short* __restrict__ hbf,
                                                 const float* __restrict__ lnw, const float* __restrict__ lnb,
                                                 const float* __restrict__ mask) {
    __shared__ unsigned short Al[2][32 * 32];
    __shared__ unsigned short Bl[2][256 * 32];
    __shared__ float part_s[32][4], part_q[32][4];
    int tid = threadIdx.x;
    int l = tid & 63;
    int w = tid >> 6;
    int m0 = blockIdx.x * 32;
    int lr = l & 15, kq = l >> 4;

    f32x4 zero = {0.f, 0.f, 0.f, 0.f};
    f32x4 acc[2][4];
#pragma unroll
    for (int i = 0; i < 2; i++)
#pragma unroll
        for (int j = 0; j < 4; j++) acc[i][j] = zero;

    auto stage = [&](int ks, int buf) {
        int k0 = ks * 32;
        if (tid < 128) {
            int row = tid >> 2, cc = (tid & 3) * 8;
            const unsigned short* ga = A + (size_t)(m0 + row) * DI + k0 + cc;
            __builtin_amdgcn_global_load_lds((const __attribute__((address_space(1))) void*)ga,
                                             (__attribute__((address_space(3))) void*)(&Al[buf][tid * 8]), 16, 0, 0);
        }
#pragma unroll
        for (int q = 0; q < 4; q++) {
            int c = tid + q * 256;
            int row = c >> 2, cc = (c & 3) * 8;
            const unsigned short* gb = Bw + (size_t)row * DI + k0 + cc;
            __builtin_amdgcn_global_load_lds((const __attribute__((address_space(1))) void*)gb,
                                             (__attribute__((address_space(3))) void*)(&Bl[buf][c * 8]), 16, 0, 0);
        }
    };

    stage(0, 0);
    const int ksteps = DI / 32;
    for (int s = 0; s < ksteps; s++) {
        int buf = s & 1;
        __syncthreads();
        if (s + 1 < ksteps) stage(s + 1, buf ^ 1);
        bf16x8 a[2], b[4];
#pragma unroll
        for (int i = 0; i < 2; i++) a[i] = *(const bf16x8*)&Al[buf][(i * 16 + lr) * 32 + kq * 8];
#pragma unroll
        for (int j = 0; j < 4; j++) b[j] = *(const bf16x8*)&Bl[buf][(w * 64 + j * 16 + lr) * 32 + kq * 8];
#pragma unroll
        for (int i = 0; i < 2; i++)
#pragma unroll
            for (int j = 0; j < 4; j++)
                acc[i][j] = __builtin_amdgcn_mfma_f32_16x16x32_bf16(a[i], b[j], acc[i][j], 0, 0, 0);
    }

#pragma unroll
    for (int i = 0; i < 2; i++) {
#pragma unroll
        for (int r = 0; r < 4; r++) {
            int row = i * 16 + kq * 4 + r;
            const unsigned short* hrow = hbf + (size_t)(m0 + row) * DM + w * 64 + lr;
#pragma unroll
            for (int j = 0; j < 4; j++)
                acc[i][j][r] += bf2f(hrow[j * 16]);
        }
    }
#pragma unroll
    for (int i = 0; i < 2; i++) {
#pragma unroll
        for (int r = 0; r < 4; r++) {
            float sv = acc[i][0][r] + acc[i][1][r] + acc[i][2][r] + acc[i][3][r];
            float qv = acc[i][0][r] * acc[i][0][r] + acc[i][1][r] * acc[i][1][r] +
                       acc[i][2][r] * acc[i][2][r] + acc[i][3][r] * acc[i][3][r];
#pragma unroll
            for (int off = 1; off < 16; off <<= 1) {
                sv += __shfl_xor(sv, off);
                qv += __shfl_xor(qv, off);
            }
            if (lr == 0) {
                int row = i * 16 + kq * 4 + r;
                part_s[row][w] = sv;
                part_q[row][w] = qv;
            }
        }
    }
    __syncthreads();
    float4 wv4 = make_float4(lnw[w * 64 + 0 * 16 + lr], lnw[w * 64 + 1 * 16 + lr],
                             lnw[w * 64 + 2 * 16 + lr], lnw[w * 64 + 3 * 16 + lr]);
    float4 bv4 = make_float4(lnb[w * 64 + 0 * 16 + lr], lnb[w * 64 + 1 * 16 + lr],
                             lnb[w * 64 + 2 * 16 + lr], lnb[w * 64 + 3 * 16 + lr]);
#pragma unroll
    for (int i = 0; i < 2; i++) {
#pragma unroll
        for (int r = 0; r < 4; r++) {
            int row = i * 16 + kq * 4 + r;
            float sum = part_s[row][0] + part_s[row][1] + part_s[row][2] + part_s[row][3];
            float sq  = part_q[row][0] + part_q[row][1] + part_q[row][2] + part_q[row][3];
            float mu = sum * (1.f / DM);
            float var = sq * (1.f / DM) - mu * mu;
            float rs = rsqrtf(var + 1e-5f);
            float mk = mask[m0 + row];
            unsigned short* drow = hbf + (size_t)(m0 + row) * DM + w * 64 + lr;
            float wr_[4] = {wv4.x, wv4.y, wv4.z, wv4.w};
            float br_[4] = {bv4.x, bv4.y, bv4.z, bv4.w};
#pragma unroll
            for (int j = 0; j < 4; j++) {
                float o = ((acc[i][j][r] - mu) * rs * wr_[j] + br_[j]) * mk;
                drow[j * 16] = f2bf(o);
            }
        }
    }
}

// ---------------- B/C conv+silu + per-head dt/cumsum precompute ----------------
__global__ __launch_bounds__(256) void k_bcdt(const unsigned short* __restrict__ zxb,
                                              const float* __restrict__ cw, const float* __restrict__ cb,
                                              const float* __restrict__ dtraw, const float* __restrict__ dtb,
                                              const float* __restrict__ Alog,
                                              unsigned short* __restrict__ BCc,
                                              float* __restrict__ dts_g, float* __restrict__ coefS_g,
                                              float* __restrict__ cumL, float* __restrict__ Pg) {
    int pair = blockIdx.x;
    int b = pair >> 5, c = pair & 31;
    int t0 = c * Q_;
    int tid = threadIdx.x;
    int t = tid & 63, oct = tid >> 6;
    {
        int lg0 = t0 + t - 3;
        const unsigned short* base = zxb + ((size_t)b * L_ + lg0) * DIP + 1024 + oct * 8;
        bf16x8 rows[4];
#pragma unroll
        for (int k = 0; k < 4; k++) {
            if (lg0 + k >= 0) rows[k] = *(const bf16x8*)(base + (size_t)k * DIP);
            else {
#pragma unroll
                for (int j = 0; j < 8; j++) rows[k][j] = 0;
            }
        }
        bf16x8 o;
#pragma unroll
        for (int j = 0; j < 8; j++) {
            int cc = DI + oct * 8 + j;
            float acc = cb[cc];
            acc = fmaf(bf2f((unsigned short)rows[0][j]), cw[cc * 4 + 0], acc);
            acc = fmaf(bf2f((unsigned short)rows[1][j]), cw[cc * 4 + 1], acc);
            acc = fmaf(bf2f((unsigned short)rows[2][j]), cw[cc * 4 + 2], acc);
            acc = fmaf(bf2f((unsigned short)rows[3][j]), cw[cc * 4 + 3], acc);
            float s = acc * fast_sig(acc);
            o[j] = (short)f2bf(s);
        }
        *(bf16x8*)(BCc + ((size_t)(b * L_ + t0 + t)) * 32 + oct * 8) = o;
    }
#pragma unroll
    for (int ho = 0; ho < 2; ho++) {
        int h = oct * 2 + ho;
        int bh = b * 8 + h;
        float raw = dtraw[(size_t)(b * L_ + t0 + t) * NH + h] + dtb[h];
        float dtv = (raw > 20.f) ? raw : log1pf(__expf(raw));
        float v = -__expf(Alog[h]) * dtv;
#pragma unroll
        for (int off = 1; off < 64; off <<= 1) {
            float u = __shfl_up(v, off);
            if (t >= off) v += u;
        }
        float lend = __shfl(v, 63);
        size_t base = (size_t)(bh * NC + c) * Q_ + t;
        dts_g[base] = dtv;
        cumL[base] = v;
        coefS_g[base] = __expf(lend - v) * dtv;
        if (t == 63) Pg[bh * NC + c] = __expf(v);
    }
}

// ---------------- fused conv+silu + chunked scan stage 1 (MFMA); vector Y store ----------------
__global__ __launch_bounds__(256) void k_scan1c(const unsigned short* __restrict__ zxb,
                                                const unsigned short* __restrict__ BCc,
                                                const float* __restrict__ dts_g, const float* __restrict__ coefS_g,
                                                const float* __restrict__ cumL,
                                                const float* __restrict__ cw, const float* __restrict__ cb,
                                                const float* __restrict__ Dp,
                                                unsigned short* __restrict__ ybuf, unsigned short* __restrict__ Sg) {
    int wg = blockIdx.x;
    int xcd = wg & 7;
    int rest = wg >> 3;
    int slot = rest >> 3;
    int h = rest & 7;
    int pair = slot * 8 + xcd;
    int b = pair >> 5, c = pair & 31;
    int bh = b * 8 + h;
    int tid = threadIdx.x;
    int t0 = c * Q_;
    int w = tid >> 6, l = tid & 63;
    int lr = l & 15, kq = l >> 4;

    __shared__ __align__(16) unsigned short Zl[67 * ZST];
    __shared__ __align__(16) unsigned short Xt[Q_ * 72];
    __shared__ __align__(16) unsigned short Pool[4096];
    __shared__ __align__(16) unsigned short Btw[DSZ * 72];
    __shared__ float Lc[Q_], dts[Q_], coefS[Q_];
    unsigned short* Mbf = Zl;
    unsigned short* Cbf = Pool;
    unsigned short* Bbf = Pool + 2048;
    unsigned short* Ylds = Pool;

    float Dval = Dp[h];

    for (int idx = tid; idx < 67 * 8; idx += 256) {
        int rr = idx >> 3, seg = idx & 7;
        int lg = t0 - 3 + rr;
        bf16x8 v;
        if (lg >= 0) {
            v = *(const bf16x8*)(zxb + (size_t)(b * L_ + lg) * DIP + DI + h * HD + seg * 8);
        } else {
#pragma unroll
            for (int j = 0; j < 8; j++) v[j] = 0;
        }
        *(ushort4*)&Zl[rr * ZST + seg * 8]     = *(ushort4*)&v;
        *(ushort4*)&Zl[rr * ZST + seg * 8 + 4] = *((ushort4*)&v + 1);
    }
    {
        bf16x8 z8;
#pragma unroll
        for (int j = 0; j < 8; j++) z8[j] = 0;
        *(bf16x8*)&Cbf[tid * 8] = z8;
        *(bf16x8*)&Bbf[tid * 8] = z8;
    }
    if (tid < 64) {
        size_t base = (size_t)(bh * NC + c) * Q_ + tid;
        dts[tid] = dts_g[base];
        Lc[tid] = cumL[base];
        coefS[tid] = coefS_g[base];
    }
    __syncthreads();

    float xreg[4][4];
#pragma unroll
    for (int pt = 0; pt < 4; pt++) {
#pragma unroll
        for (int r = 0; r < 4; r++) {
            int t = w * 16 + kq * 4 + r;
            int p = pt * 16 + lr;
            int cc = h * HD + p;
            float acc = cb[cc];
#pragma unroll
            for (int k = 0; k < 4; k++)
                acc = fmaf(bf2f(Zl[(t + k) * ZST + p]), cw[cc * 4 + k], acc);
            float s = acc * fast_sig(acc);
            xreg[pt][r] = s;
            Xt[p * 72 + t] = f2bf(s);
        }
    }
    {
        int t = tid & 63, oct = tid >> 6;
        bf16x8 v = *(const bf16x8*)(BCc + ((size_t)(b * L_ + t0 + t)) * 32 + oct * 8);
        float dtv = dts[t], cfv = coefS[t];
#pragma unroll
        for (int j = 0; j < 8; j++) {
            int n32 = oct * 8 + j;
            float s = bf2f((unsigned short)v[j]);
            if (n32 < 16) {
                int n = n32;
                Bbf[t * 32 + (((n >> 3) ^ (t & 3)) * 8) + (n & 7)] = f2bf(dtv * s);
                Btw[n * 72 + t] = f2bf(cfv * s);
            } else {
                int n = n32 - 16;
                Cbf[t * 32 + (((n >> 3) ^ (t & 3)) * 8) + (n & 7)] = (unsigned short)v[j];
            }
        }
    }
    __syncthreads();

    f32x4 zero = {0.f, 0.f, 0.f, 0.f};

    f32x4 cbt[4];
    {
        bf16x8 af = *(const bf16x8*)&Cbf[(w * 16 + lr) * 32 + ((kq ^ (lr & 3)) * 8)];
#pragma unroll
        for (int st = 0; st < 4; st++) {
            bf16x8 bf = *(const bf16x8*)&Bbf[(st * 16 + lr) * 32 + ((kq ^ (lr & 3)) * 8)];
            cbt[st] = __builtin_amdgcn_mfma_f32_16x16x32_bf16(af, bf, zero, 0, 0, 0);
        }
    }
#pragma unroll
    for (int st = 0; st < 4; st++) {
#pragma unroll
        for (int r = 0; r < 4; r++) {
            int t = w * 16 + kq * 4 + r;
            int s = st * 16 + lr;
            float m = (s <= t) ? __expf(Lc[t] - Lc[s]) * cbt[st][r] : 0.f;
            Mbf[t * 64 + (((s >> 3) ^ (t & 7)) * 8) + (s & 7)] = f2bf(m);
        }
    }
    __syncthreads();

    {
        f32x4 acc[4];
#pragma unroll
        for (int pt = 0; pt < 4; pt++) acc[pt] = zero;
#pragma unroll
        for (int ks = 0; ks < 2; ks++) {
            bf16x8 af = *(const bf16x8*)&Mbf[(w * 16 + lr) * 64 + (((ks * 4 + kq) ^ (lr & 7)) * 8)];
#pragma unroll
            for (int pt = 0; pt < 4; pt++) {
                bf16x8 bf = *(const bf16x8*)&Xt[(pt * 16 + lr) * 72 + ks * 32 + kq * 8];
                acc[pt] = __builtin_amdgcn_mfma_f32_16x16x32_bf16(af, bf, acc[pt], 0, 0, 0);
            }
        }
#pragma unroll
        for (int pt = 0; pt < 4; pt++) {
#pragma unroll
            for (int r = 0; r < 4; r++) {
                int t = w * 16 + kq * 4 + r;
                int p = pt * 16 + lr;
                Ylds[t * 64 + p] = f2bf(acc[pt][r] + Dval * xreg[pt][r]);
            }
        }
    }

    {
        f32x4 sacc = zero;
#pragma unroll
        for (int ks = 0; ks < 2; ks++) {
            bf16x8 af = *(const bf16x8*)&Xt[(w * 16 + lr) * 72 + ks * 32 + kq * 8];
            bf16x8 bf = *(const bf16x8*)&Btw[lr * 72 + ks * 32 + kq * 8];
            sacc = __builtin_amdgcn_mfma_f32_16x16x32_bf16(af, bf, sacc, 0, 0, 0);
        }
#pragma unroll
        for (int r = 0; r < 4; r++) {
            int p = w * 16 + kq * 4 + r;
            Sg[((size_t)(bh * NC + c) * HD + p) * DSZ + lr] = f2bf(sacc[r]);
        }
    }
    __syncthreads();

    {
        unsigned short* base_y = ybuf + ((size_t)b * L_ + t0) * DI + h * HD;
#pragma unroll
        for (int q = 0; q < 2; q++) {
            int idx = q * 256 + tid;
            int t = idx >> 3, oct = idx & 7;
            *(bf16x8*)(base_y + (size_t)t * DI + oct * 8) = *(const bf16x8*)&Ylds[t * 64 + oct * 8];
        }
    }
}

// ---------------- chunked scan stage 2: bf16 S/H, fp32 prefix in registers ----------------
__global__ __launch_bounds__(256) void k_scan2(const unsigned short* __restrict__ Sg, const float* __restrict__ Pg,
                                               unsigned short* __restrict__ Hg) {
    int bh = blockIdx.x;
    int tid = threadIdx.x;
    int p = tid >> 2, n0 = (tid & 3) * 4;
    float4 H = make_float4(0.f, 0.f, 0.f, 0.f);
    for (int g = 0; g < NC / 8; g++) {
        ushort4 S[8];
#pragma unroll
        for (int j = 0; j < 8; j++)
            S[j] = *(const ushort4*)(Sg + (((size_t)bh * NC + g * 8 + j) * HD + p) * DSZ + n0);
#pragma unroll
        for (int j = 0; j < 8; j++) {
            int cc = g * 8 + j;
            ushort4 ho;
            ho.x = f2bf(H.x); ho.y = f2bf(H.y); ho.z = f2bf(H.z); ho.w = f2bf(H.w);
            *(ushort4*)(Hg + (((size_t)bh * NC + cc) * HD + p) * DSZ + n0) = ho;
            float P = Pg[bh * NC + cc];
            H.x = fmaf(P, H.x, bf2f(S[j].x));
            H.y = fmaf(P, H.y, bf2f(S[j].y));
            H.z = fmaf(P, H.z, bf2f(S[j].z));
            H.w = fmaf(P, H.w, bf2f(S[j].w));
        }
    }
}

// ---------------- fused scan stage 3 + gated RMSNorm -> bf16 yn (XCD-swizzled grid 1024) ----------------
__global__ __launch_bounds__(256) void k_scan3g(const unsigned short* __restrict__ ybuf,
                                                const unsigned short* __restrict__ zxb,
                                                const unsigned short* __restrict__ Hg, const float* __restrict__ cumLg,
                                                const unsigned short* __restrict__ BCc, const float* __restrict__ nw,
                                                unsigned short* __restrict__ yn_bf) {
    int wg = blockIdx.x;
    int xcd = wg & 7;
    int rest = wg >> 3;                 // 0..127
    int chunk_local = rest >> 2;        // 0..31
    int sub = rest & 3;
    int chunk_global = xcd * 32 + chunk_local;   // 0..255
    int b = chunk_global >> 5, c64 = chunk_global & 31;
    int tl0 = sub * 16;
    int t0 = c64 * 64 + sub * 16;
    int tid = threadIdx.x;
    __shared__ float Hsn[DSZ * 576];
    __shared__ float Lq[NH][16];

    {
        int p = tid & 63, hp = tid >> 6;
#pragma unroll
        for (int ho = 0; ho < 2; ho++) {
            int hh = hp * 2 + ho;
            const unsigned short* src = Hg + (((size_t)(b * NH + hh) * NC + c64) * HD + p) * DSZ;
            float* dst = &Hsn[p * 9 + hh];
            bf16x8 lo = *(const bf16x8*)(src);
            bf16x8 hi = *(const bf16x8*)(src + 8);
#pragma unroll
            for (int nq = 0; nq < 8; nq++) {
                dst[nq * 576] = bf2f((unsigned short)lo[nq]);
                dst[(nq + 8) * 576] = bf2f((unsigned short)hi[nq]);
            }
        }
    }
    if (tid < 128) {
        int hh = tid >> 4, t = tid & 15;
        Lq[hh][t] = cumLg[((size_t)(b * NH + hh) * NC + c64) * Q_ + tl0 + t];
    }
    __syncthreads();

    int t = tid >> 4, q = tid & 15;
    int hh = q >> 1, p0 = (q & 1) * 32;
    size_t bl = (size_t)b * L_ + t0 + t;
    float ef = __expf(Lq[hh][t]);

    float Cr[16];
    {
        const unsigned short* crow = BCc + bl * 32 + 16;
        bf16x8 lo = *(const bf16x8*)(crow);
        bf16x8 hi = *(const bf16x8*)(crow + 8);
#pragma unroll
        for (int k = 0; k < 8; k++) {
            Cr[k] = ef * bf2f((unsigned short)lo[k]);
            Cr[k + 8] = ef * bf2f((unsigned short)hi[k]);
        }
    }

    const unsigned short* yrow = ybuf + bl * DI + hh * HD + p0;
    const unsigned short* zrow = zxb + bl * DIP + hh * HD + p0;
    unsigned short yv[32], zv[32];
#pragma unroll
    for (int k = 0; k < 4; k++) *(bf16x8*)&yv[k * 8] = *(const bf16x8*)(yrow + k * 8);
#pragma unroll
    for (int k = 0; k < 4; k++) *(bf16x8*)&zv[k * 8] = *(const bf16x8*)(zrow + k * 8);

    float yg[32];
    float ss = 0.f;
#pragma unroll
    for (int j = 0; j < 32; j++) {
        const float* hp_ = &Hsn[(p0 + j) * 9 + hh];
        float d = 0.f;
#pragma unroll
        for (int n = 0; n < DSZ; n++) d = fmaf(Cr[n], hp_[n * 576], d);
        float y = bf2f(yv[j]) + d;
        float z = bf2f(zv[j]);
        yg[j] = y * z * fast_sig(z);
        ss = fmaf(yg[j], yg[j], ss);
    }
    ss += __shfl_xor(ss, 1);
    ss += __shfl_xor(ss, 2);
    ss += __shfl_xor(ss, 4);
    ss += __shfl_xor(ss, 8);
    float r = rsqrtf(ss * (1.f / DI) + 1e-5f);

    const float* nwp = nw + hh * HD + p0;
    unsigned short* dst = yn_bf + bl * DI + hh * HD + p0;
#pragma unroll
    for (int k = 0; k < 4; k++) {
        bf16x8 o;
#pragma unroll
        for (int j = 0; j < 8; j++) o[j] = (short)f2bf(yg[k * 8 + j] * r * nwp[k * 8 + j]);
        *(bf16x8*)(dst + k * 8) = o;
    }
}

// ---------------- 2-stage mean-pool + classifier (bf16 input) ----------------
__global__ __launch_bounds__(256) void k_pool1(const unsigned short* __restrict__ h, float* __restrict__ part) {
    int b = blockIdx.x, g = blockIdx.y, d = threadIdx.x;
    const unsigned short* hb = h + ((size_t)b * L_ + g * 128) * DM + d;
    float s = 0.f;
    for (int l = 0; l < 128; l++) s += bf2f(hb[(size_t)l * DM]);
    part[((size_t)b * 16 + g) * DM + d] = s;
}

__global__ __launch_bounds__(256) void k_pool2(const float* __restrict__ part, const float* __restrict__ cw,
                                               const float* __restrict__ cb, float* __restrict__ out) {
    int b = blockIdx.x, tid = threadIdx.x;
    float s = 0.f;
#pragma unroll
    for (int g = 0; g < 16; g++) s += part[((size_t)b * 16 + g) * DM + tid];
    s *= (1.0f / L_);
    float p0 = s * cw[tid];
    float p1 = s * cw[DM + tid];
#pragma unroll
    for (int m = 1; m < 64; m <<= 1) {
        p0 += __shfl_xor(p0, m);
        p1 += __shfl_xor(p1, m);
    }
    __shared__ float r0[4], r1[4];
    if ((tid & 63) == 0) { r0[tid >> 6] = p0; r1[tid >> 6] = p1; }
    __syncthreads();
    if (tid == 0) {
        out[b * 2 + 0] = r0[0] + r0[1] + r0[2] + r0[3] + cb[0];
        out[b * 2 + 1] = r1[0] + r1[1] + r1[2] + r1[3] + cb[1];
    }
}

extern "C" void kernel_launch(void* const* d_in, const int* in_sizes, int n_in,
                              void* d_out, int out_size, void* d_ws, size_t ws_size,
                              hipStream_t stream) {
    const int*   x    = (const int*)d_in[0];
    const float* mask = (const float*)d_in[1];
    const float* emb  = (const float*)d_in[2];
    const float* pos  = (const float*)d_in[3];
    const float* Wi   = (const float*)d_in[4];
    const float* cw   = (const float*)d_in[5];
    const float* cb   = (const float*)d_in[6];
    const float* dtb  = (const float*)d_in[7];
    const float* Alog = (const float*)d_in[8];
    const float* Dp   = (const float*)d_in[9];
    const float* nw   = (const float*)d_in[10];
    const float* Wo   = (const float*)d_in[11];
    const float* lnw  = (const float*)d_in[12];
    const float* lnb  = (const float*)d_in[13];
    const float* clsw = (const float*)d_in[14];
    const float* clsb = (const float*)d_in[15];
    float* out = (float*)d_out;

    float* ws     = (float*)d_ws;
    float* dtraw  = ws;
    float* Pg     = dtraw + (size_t)B_ * L_ * NH;
    float* cumL   = Pg + (size_t)64 * NC;
    float* dts_g  = cumL + (size_t)64 * NC * Q_;
    float* coefSg = dts_g + (size_t)64 * NC * Q_;
    float* pool   = coefSg + (size_t)64 * NC * Q_;
    unsigned short* Sg    = (unsigned short*)(pool + (size_t)B_ * 16 * DM);
    unsigned short* Hg    = Sg + (size_t)64 * NC * HD * DSZ;
    unsigned short* BCc   = Hg + (size_t)64 * NC * HD * DSZ;
    unsigned short* zxb   = BCc + (size_t)B_ * L_ * 32;
    unsigned short* ybuf  = zxb + (size_t)B_ * L_ * DIP;
    unsigned short* h_bf  = ybuf + (size_t)B_ * L_ * DI;
    unsigned short* yn_bf = h_bf + (size_t)B_ * L_ * DM;
    unsigned short* Wi_bf = yn_bf + (size_t)B_ * L_ * DI;
    unsigned short* Wo_bf = Wi_bf + (size_t)4 * DIP * DM;

    // merged prologue: embed + weight conversions
    k_init<<<16384 + 1064 + 512, 256, 0, stream>>>(x, mask, emb, pos, h_bf, Wi, Wi_bf, Wo, Wo_bf);

    for (int i = 0; i < 4; i++) {
        k_gemm_in<<<128 * 9, 256, 0, stream>>>(
            h_bf, Wi_bf + (size_t)i * DIP * DM, zxb, dtraw);
        k_bcdt<<<B_ * NC, 256, 0, stream>>>(
            zxb, cw + (size_t)i * CD * 4, cb + i * CD, dtraw, dtb + i * NH, Alog + i * NH,
            BCc, dts_g, coefSg, cumL, Pg);
        k_scan1c<<<2048, 256, 0, stream>>>(
            zxb, BCc, dts_g, coefSg, cumL, cw + (size_t)i * CD * 4, cb + i * CD,
            Dp + i * NH, ybuf, Sg);
        k_scan2<<<64, 256, 0, stream>>>(Sg, Pg, Hg);
        k_scan3g<<<1024, 256, 0, stream>>>(ybuf, zxb, Hg, cumL, BCc, nw + (size_t)i * DI, yn_bf);
        k_gemm_ln<<<B_ * L_ / 32, 256, 0, stream>>>(
            yn_bf, Wo_bf + (size_t)i * DM * DI, h_bf, lnw, lnb, mask);
    }

    k_pool1<<<dim3(B_, 16), 256, 0, stream>>>(h_bf, pool);
    k_pool2<<<B_, 256, 0, stream>>>(pool, clsw, clsb, out);
}